// Round 6
// baseline (178.008 us; speedup 1.0000x reference)
//
#include <hip/hip_runtime.h>
#include <hip/hip_bf16.h>

#define C_DIM 8192
#define E_DIM 512

using f32x4 = __attribute__((ext_vector_type(4))) float;
using s16x8 = __attribute__((ext_vector_type(8))) short;

__device__ inline void gload_lds16(const void* g, void* l) {
  __builtin_amdgcn_global_load_lds(
      (const __attribute__((address_space(1))) unsigned*)g,
      (__attribute__((address_space(3))) unsigned*)l, 16, 0, 0);
}

__device__ inline unsigned pack_bf16(float a, float b) {
  unsigned ua = __float_as_uint(a), ub = __float_as_uint(b);
  ua = (ua + 0x7fffu + ((ua >> 16) & 1u)) >> 16;
  ub = (ub + 0x7fffu + ((ub >> 16) & 1u)) >> 16;
  return ua | (ub << 16);
}

__device__ inline float bf2f(unsigned short u) {
  return __uint_as_float(((unsigned)u) << 16);
}

// ---------------- Kernel 1: row L2 normalize -> bf16 only -------------------
__global__ __launch_bounds__(256) void norm_kernel(
    const float* __restrict__ P, unsigned* __restrict__ Pb) {
  int wid = threadIdx.x >> 6, lane = threadIdx.x & 63;
  int row = blockIdx.x * 4 + wid;
  const float4* src = (const float4*)(P + (size_t)row * E_DIM);
  float4 v0 = src[lane], v1 = src[lane + 64];
  float ss = v0.x * v0.x + v0.y * v0.y + v0.z * v0.z + v0.w * v0.w +
             v1.x * v1.x + v1.y * v1.y + v1.z * v1.z + v1.w * v1.w;
  for (int m = 32; m; m >>= 1) ss += __shfl_xor(ss, m);
  float inv = 1.0f / fmaxf(sqrtf(ss), 1e-12f);
  v0.x *= inv; v0.y *= inv; v0.z *= inv; v0.w *= inv;
  v1.x *= inv; v1.y *= inv; v1.z *= inv; v1.w *= inv;
  uint2* bd = (uint2*)(Pb + (size_t)row * (E_DIM / 2));
  uint2 b0, b1;
  b0.x = pack_bf16(v0.x, v0.y); b0.y = pack_bf16(v0.z, v0.w);
  b1.x = pack_bf16(v1.x, v1.y); b1.y = pack_bf16(v1.z, v1.w);
  bd[lane] = b0; bd[lane + 64] = b1;
}

// ---------------- Kernel 2: q = column sums of Pb (bf16) --------------------
__global__ __launch_bounds__(256) void qsum_kernel(
    const unsigned short* __restrict__ Pb, float* __restrict__ q) {
  __shared__ float red[4][512];
  int wid = threadIdx.x >> 6, lane = threadIdx.x & 63;
  float a[8];
#pragma unroll
  for (int k = 0; k < 8; ++k) a[k] = 0.f;
  for (int i = 0; i < 32; ++i) {
    int row = blockIdx.x * 128 + wid * 32 + i;
    uint4 v = *(const uint4*)(Pb + (size_t)row * E_DIM + lane * 8);
    a[0] += bf2f((unsigned short)(v.x & 0xffff));
    a[1] += bf2f((unsigned short)(v.x >> 16));
    a[2] += bf2f((unsigned short)(v.y & 0xffff));
    a[3] += bf2f((unsigned short)(v.y >> 16));
    a[4] += bf2f((unsigned short)(v.z & 0xffff));
    a[5] += bf2f((unsigned short)(v.z >> 16));
    a[6] += bf2f((unsigned short)(v.w & 0xffff));
    a[7] += bf2f((unsigned short)(v.w >> 16));
  }
#pragma unroll
  for (int k = 0; k < 8; ++k) red[wid][lane * 8 + k] = a[k];
  __syncthreads();
  for (int c = threadIdx.x; c < 512; c += 256) {
    float t = red[0][c] + red[1][c] + red[2][c] + red[3][c];
    atomicAdd(&q[c], t);
  }
}

// ---------------- Kernel 3: s_j = dot(Pb[j], q) -----------------------------
__global__ __launch_bounds__(256) void ssum_kernel(
    const unsigned short* __restrict__ Pb, const float* __restrict__ q,
    float* __restrict__ s) {
  int wid = threadIdx.x >> 6, lane = threadIdx.x & 63;
  int row = blockIdx.x * 4 + wid;
  uint4 v = *(const uint4*)(Pb + (size_t)row * E_DIM + lane * 8);
  const float4* qv = (const float4*)q;
  float4 q0 = qv[lane * 2], q1 = qv[lane * 2 + 1];
  float d = bf2f((unsigned short)(v.x & 0xffff)) * q0.x +
            bf2f((unsigned short)(v.x >> 16)) * q0.y +
            bf2f((unsigned short)(v.y & 0xffff)) * q0.z +
            bf2f((unsigned short)(v.y >> 16)) * q0.w +
            bf2f((unsigned short)(v.z & 0xffff)) * q1.x +
            bf2f((unsigned short)(v.z >> 16)) * q1.y +
            bf2f((unsigned short)(v.w & 0xffff)) * q1.z +
            bf2f((unsigned short)(v.w >> 16)) * q1.w;
  for (int m = 32; m; m >>= 1) d += __shfl_xor(d, m);
  if (lane == 0) s[row] = d;
}

// ---------------- Kernel 4: barrier-free panel-sweep Gram -------------------
// Each block: 8 waves, A panel [128 rows][512 k] bf16 = 128KB in LDS (staged
// once per panel, XOR-swizzled via pre-swizzled global source). B fragments
// streamed DIRECTLY from global (L2-resident) - no per-K-step barriers.
// Block processes 2 pair-units; a pair-unit = 128x256 region (tiles bx0,bx0+1
// of row-panel by; odd rows have a trailing guarded singleton).
// Partials written to collision-free slices Zp/Sp[rb=64][slot=256][rowin=128]:
//   row-type: slot = (bx-rb)*2 + wc (wc = col-half within tile), bx >= rb
//   col-type: slot = 128 + by*2 + wr (mirror, by < rb)
__global__ __launch_bounds__(512, 2) void gram_kernel(
    const unsigned short* __restrict__ Pb, float* __restrict__ Zp,
    float* __restrict__ Sp) {
  __shared__ unsigned short As[128 * 512];  // 128 KB

  int tid = threadIdx.x, wid = tid >> 6, lane = tid & 63;
  int wr = wid >> 2, wc4 = wid & 3;  // 2 x 4 wave grid over 128x256 region
  int l15 = lane & 15, lh = lane >> 4;

  // XCD-aware bijective remap: 528 = 8 * 66
  int b = blockIdx.x;
  int ii = (b & 7) * 66 + (b >> 3);

  int curBy = -1;

  for (int pu = 0; pu < 2; ++pu) {
    int pi = ii * 2 + pu;  // 0..1055 pair index
    // decode: u = row-pair id, C(u) = u*(65-u)
    float disc = sqrtf(4225.0f - 4.0f * (float)pi);
    int u = (int)((65.0f - disc) * 0.5f);
    if (u < 0) u = 0;
    while ((u + 1) * (65 - (u + 1)) <= pi) ++u;
    while (u * (65 - u) > pi) --u;
    int rem = pi - u * (65 - u);
    int by, j;
    if (rem < 32 - u) { by = 2 * u; j = rem; }
    else { by = 2 * u + 1; j = rem - (32 - u); }
    int bx0 = by + 2 * j;
    bool valid1 = (bx0 + 1) <= 63;

    // (re)stage A panel if row-panel changed
    if (by != curBy) {
      __syncthreads();  // all waves done reading old panel
      int w16 = wid * 16;
#pragma unroll
      for (int it = 0; it < 16; ++it) {
        int r = w16 + it;
        const unsigned short* src =
            Pb + (size_t)(by * 128 + r) * E_DIM + ((lane ^ (r & 7)) * 8);
        gload_lds16(src, (char*)As + r * 1024);
      }
      __syncthreads();  // drains vmcnt -> panel visible
      curBy = by;
    }

    f32x4 acc[4][4];
#pragma unroll
    for (int m = 0; m < 4; ++m)
#pragma unroll
      for (int n = 0; n < 4; ++n)
        acc[m][n] = (f32x4){0.f, 0.f, 0.f, 0.f};

    // B row addresses (clamped; singleton's phantom tile reads in-bounds junk)
    size_t rB[4];
#pragma unroll
    for (int n = 0; n < 4; ++n) {
      int row = bx0 * 128 + wc4 * 64 + n * 16 + l15;
      rB[n] = (size_t)min(row, C_DIM - 1) * E_DIM;
    }

#pragma unroll
    for (int kk = 0; kk < 16; ++kk) {
      s16x8 af[4], bf[4];
#pragma unroll
      for (int n = 0; n < 4; ++n)
        bf[n] = *(const s16x8*)(Pb + rB[n] + kk * 32 + lh * 8);
#pragma unroll
      for (int m = 0; m < 4; ++m) {
        int row = wr * 64 + m * 16 + l15;
        int slot = (kk * 4 + lh) ^ (l15 & 7);
        af[m] = *(const s16x8*)(As + (size_t)row * 512 + slot * 8);
      }
#pragma unroll
      for (int m = 0; m < 4; ++m)
#pragma unroll
        for (int n = 0; n < 4; ++n)
          acc[m][n] = __builtin_amdgcn_mfma_f32_16x16x32_bf16(
              af[m], bf[n], acc[m][n], 0, 0, 0);
    }

    // epilogue
    int bx_t = bx0 + (wc4 >> 1);
    bool tileValid = (wc4 < 2) || valid1;
    float zc[4], sc[4];
#pragma unroll
    for (int n = 0; n < 4; ++n) { zc[n] = 0.f; sc[n] = 0.f; }

    int slotR = (bx_t - by) * 2 + (wc4 & 1);
#pragma unroll
    for (int m = 0; m < 4; ++m) {
#pragma unroll
      for (int reg = 0; reg < 4; ++reg) {
        float z = 0.f, s = 0.f;
#pragma unroll
        for (int n = 0; n < 4; ++n) {
          float g = acc[m][n][reg];
          float e = __expf(g);
          z += e;
          s += e * g;
          zc[n] += e;
          sc[n] += e * g;
        }
        for (int msk = 8; msk; msk >>= 1) {
          z += __shfl_xor(z, msk);
          s += __shfl_xor(s, msk);
        }
        if (l15 == 0 && tileValid) {
          int rowin = wr * 64 + m * 16 + lh * 4 + reg;
          size_t idx = ((size_t)by * 256 + slotR) * 128 + rowin;
          Zp[idx] = z;
          Sp[idx] = s;
        }
      }
    }
    if (tileValid && bx_t != by) {
      int slotC = 128 + by * 2 + wr;
#pragma unroll
      for (int n = 0; n < 4; ++n) {
        float z = zc[n], s = sc[n];
        z += __shfl_xor(z, 16); s += __shfl_xor(s, 16);
        z += __shfl_xor(z, 32); s += __shfl_xor(s, 32);
        if (lh == 0) {
          int colin = (wc4 & 1) * 64 + n * 16 + l15;
          size_t idx = ((size_t)bx_t * 256 + slotC) * 128 + colin;
          Zp[idx] = z;
          Sp[idx] = s;
        }
      }
    }
  }
}

// ---------------- Kernel 5: fold slots -> per-row entropy -------------------
// Block rb: rows rb*128..+128. Valid slots: [0,(64-rb)*2) row-type and
// [128,128+2*rb) col-type. Threads 0..127 sum Z, 128..255 sum S.
__global__ __launch_bounds__(256) void reduce_kernel(
    const float* __restrict__ Zp, const float* __restrict__ Sp,
    float* __restrict__ Hrow) {
  __shared__ float zbuf[128], sbuf[128];
  int rb = blockIdx.x;
  int t = threadIdx.x;
  int row = t & 127;
  const float* src = (t >= 128) ? Sp : Zp;
  size_t base = (size_t)rb * 256 * 128 + row;
  float acc = 0.f;
  int c1 = (64 - rb) * 2;
  for (int sl = 0; sl < c1; ++sl) acc += src[base + (size_t)sl * 128];
  int c2 = 128 + 2 * rb;
  for (int sl = 128; sl < c2; ++sl) acc += src[base + (size_t)sl * 128];
  if (t >= 128) sbuf[row] = acc; else zbuf[row] = acc;
  __syncthreads();
  if (t < 128) {
    float z = zbuf[t], s2 = sbuf[t];
    Hrow[rb * 128 + t] = logf(z) - s2 / z;
  }
}

// ---------------- Kernel 6: finalize ----------------------------------------
__device__ inline float bsum(float v, volatile float* red) {
  int lane = threadIdx.x & 63, wid = threadIdx.x >> 6;
  for (int k = 32; k; k >>= 1) v += __shfl_xor(v, k);
  __syncthreads();
  if (lane == 0) red[wid] = v;
  __syncthreads();
  float r = 0.f;
  if (wid == 0) {
    r = (lane < 16) ? red[lane] : 0.f;
    for (int k = 8; k; k >>= 1) r += __shfl_xor(r, k);
  }
  if (threadIdx.x == 0) red[16] = r;
  __syncthreads();
  return red[16];
}

__device__ inline float bmax(float v, volatile float* red) {
  int lane = threadIdx.x & 63, wid = threadIdx.x >> 6;
  for (int k = 32; k; k >>= 1) v = fmaxf(v, __shfl_xor(v, k));
  __syncthreads();
  if (lane == 0) red[wid] = v;
  __syncthreads();
  float r = -3.4e38f;
  if (wid == 0) {
    r = (lane < 16) ? red[lane] : -3.4e38f;
    for (int k = 8; k; k >>= 1) r = fmaxf(r, __shfl_xor(r, k));
  }
  if (threadIdx.x == 0) red[16] = r;
  __syncthreads();
  return red[16];
}

__global__ __launch_bounds__(1024) void final_kernel(
    const float* __restrict__ s, const float* __restrict__ Hrow,
    float* __restrict__ out) {
  __shared__ float red[17];
  int tid = threadIdx.x;

  float m = -3.4e38f;
  for (int i = tid; i < C_DIM; i += 1024) m = fmaxf(m, s[i]);
  m = bmax(m, red);

  float z = 0.f, sw = 0.f;
  for (int i = tid; i < C_DIM; i += 1024) {
    float t = s[i] - m;
    float e = __expf(t);
    z += e;
    sw += e * t;
  }
  z = bsum(z, red);
  sw = bsum(sw, red);
  float H2 = logf(z) - sw / z;

  float h = 0.f;
  for (int i = tid; i < C_DIM; i += 1024) h += Hrow[i];
  h = bsum(h, red);

  if (tid == 0) out[0] = h / (float)C_DIM + H2;
}

extern "C" void kernel_launch(void* const* d_in, const int* in_sizes, int n_in,
                              void* d_out, int out_size, void* d_ws, size_t ws_size,
                              hipStream_t stream) {
  const float* P = (const float*)d_in[0];
  float* out = (float*)d_out;

  char* ws = (char*)d_ws;
  unsigned* Pb = (unsigned*)ws;                                    // 8 MB (bf16)
  float* Zp = (float*)(ws + ((size_t)8 << 20));                    // 8 MB
  float* Sp = (float*)(ws + ((size_t)16 << 20));                   // 8 MB
  float* q = (float*)(ws + ((size_t)24 << 20));                    // 2 KB
  float* s = (float*)(ws + ((size_t)24 << 20) + 4096);             // 32 KB
  float* Hrow = (float*)(ws + ((size_t)24 << 20) + 4096 + 32768);  // 32 KB

  hipMemsetAsync(q, 0, 2048, stream);  // only q needs zeroing

  norm_kernel<<<C_DIM / 4, 256, 0, stream>>>(P, Pb);
  qsum_kernel<<<C_DIM / 128, 256, 0, stream>>>((const unsigned short*)Pb, q);
  ssum_kernel<<<C_DIM / 4, 256, 0, stream>>>((const unsigned short*)Pb, q, s);
  gram_kernel<<<528, 512, 0, stream>>>((const unsigned short*)Pb, Zp, Sp);
  reduce_kernel<<<64, 256, 0, stream>>>(Zp, Sp, Hrow);
  final_kernel<<<1, 1024, 0, stream>>>(s, Hrow, out);
}

// Round 7
// 82.547 us; speedup vs baseline: 2.1564x; 2.1564x over previous
//
#include <hip/hip_runtime.h>
#include <hip/hip_bf16.h>

#define C_DIM 8192
#define E_DIM 512

using f32x4 = __attribute__((ext_vector_type(4))) float;
using i32x4 = __attribute__((ext_vector_type(4))) int;

__device__ inline void gload_lds16(const void* g, void* l) {
  __builtin_amdgcn_global_load_lds(
      (const __attribute__((address_space(1))) unsigned*)g,
      (__attribute__((address_space(3))) unsigned*)l, 16, 0, 0);
}

__device__ inline unsigned pack_bf16(float a, float b) {
  unsigned ua = __float_as_uint(a), ub = __float_as_uint(b);
  ua = (ua + 0x7fffu + ((ua >> 16) & 1u)) >> 16;
  ub = (ub + 0x7fffu + ((ub >> 16) & 1u)) >> 16;
  return ua | (ub << 16);
}

__device__ inline float bf2f(unsigned short u) {
  return __uint_as_float(((unsigned)u) << 16);
}

__device__ inline unsigned pack_i8x4(float a, float b, float c, float d) {
  unsigned x0 = (unsigned)(__float2int_rn(a * 127.f)) & 255u;
  unsigned x1 = (unsigned)(__float2int_rn(b * 127.f)) & 255u;
  unsigned x2 = (unsigned)(__float2int_rn(c * 127.f)) & 255u;
  unsigned x3 = (unsigned)(__float2int_rn(d * 127.f)) & 255u;
  return x0 | (x1 << 8) | (x2 << 16) | (x3 << 24);
}

// ------- Kernel 1: row L2 normalize -> bf16 (for q/s path) + i8 (for Gram) --
__global__ __launch_bounds__(256) void norm_kernel(
    const float* __restrict__ P, unsigned* __restrict__ Pb,
    unsigned* __restrict__ Pi) {
  int wid = threadIdx.x >> 6, lane = threadIdx.x & 63;
  int row = blockIdx.x * 4 + wid;
  const float4* src = (const float4*)(P + (size_t)row * E_DIM);
  float4 v0 = src[lane], v1 = src[lane + 64];
  float ss = v0.x * v0.x + v0.y * v0.y + v0.z * v0.z + v0.w * v0.w +
             v1.x * v1.x + v1.y * v1.y + v1.z * v1.z + v1.w * v1.w;
  for (int m = 32; m; m >>= 1) ss += __shfl_xor(ss, m);
  float inv = 1.0f / fmaxf(sqrtf(ss), 1e-12f);
  v0.x *= inv; v0.y *= inv; v0.z *= inv; v0.w *= inv;
  v1.x *= inv; v1.y *= inv; v1.z *= inv; v1.w *= inv;
  uint2* bd = (uint2*)(Pb + (size_t)row * (E_DIM / 2));
  uint2 b0, b1;
  b0.x = pack_bf16(v0.x, v0.y); b0.y = pack_bf16(v0.z, v0.w);
  b1.x = pack_bf16(v1.x, v1.y); b1.y = pack_bf16(v1.z, v1.w);
  bd[lane] = b0; bd[lane + 64] = b1;
  Pi[(size_t)row * 128 + lane] = pack_i8x4(v0.x, v0.y, v0.z, v0.w);
  Pi[(size_t)row * 128 + 64 + lane] = pack_i8x4(v1.x, v1.y, v1.z, v1.w);
}

// ---------------- Kernel 2: q = column sums of Pb (bf16) --------------------
__global__ __launch_bounds__(256) void qsum_kernel(
    const unsigned short* __restrict__ Pb, float* __restrict__ q) {
  __shared__ float red[4][512];
  int wid = threadIdx.x >> 6, lane = threadIdx.x & 63;
  float a[8];
#pragma unroll
  for (int k = 0; k < 8; ++k) a[k] = 0.f;
  for (int i = 0; i < 32; ++i) {
    int row = blockIdx.x * 128 + wid * 32 + i;
    uint4 v = *(const uint4*)(Pb + (size_t)row * E_DIM + lane * 8);
    a[0] += bf2f((unsigned short)(v.x & 0xffff));
    a[1] += bf2f((unsigned short)(v.x >> 16));
    a[2] += bf2f((unsigned short)(v.y & 0xffff));
    a[3] += bf2f((unsigned short)(v.y >> 16));
    a[4] += bf2f((unsigned short)(v.z & 0xffff));
    a[5] += bf2f((unsigned short)(v.z >> 16));
    a[6] += bf2f((unsigned short)(v.w & 0xffff));
    a[7] += bf2f((unsigned short)(v.w >> 16));
  }
#pragma unroll
  for (int k = 0; k < 8; ++k) red[wid][lane * 8 + k] = a[k];
  __syncthreads();
  for (int c = threadIdx.x; c < 512; c += 256) {
    float t = red[0][c] + red[1][c] + red[2][c] + red[3][c];
    atomicAdd(&q[c], t);
  }
}

// ---------------- Kernel 3: s_j = dot(Pb[j], q) -----------------------------
__global__ __launch_bounds__(256) void ssum_kernel(
    const unsigned short* __restrict__ Pb, const float* __restrict__ q,
    float* __restrict__ s) {
  int wid = threadIdx.x >> 6, lane = threadIdx.x & 63;
  int row = blockIdx.x * 4 + wid;
  uint4 v = *(const uint4*)(Pb + (size_t)row * E_DIM + lane * 8);
  const float4* qv = (const float4*)q;
  float4 q0 = qv[lane * 2], q1 = qv[lane * 2 + 1];
  float d = bf2f((unsigned short)(v.x & 0xffff)) * q0.x +
            bf2f((unsigned short)(v.x >> 16)) * q0.y +
            bf2f((unsigned short)(v.y & 0xffff)) * q0.z +
            bf2f((unsigned short)(v.y >> 16)) * q0.w +
            bf2f((unsigned short)(v.z & 0xffff)) * q1.x +
            bf2f((unsigned short)(v.z >> 16)) * q1.y +
            bf2f((unsigned short)(v.w & 0xffff)) * q1.z +
            bf2f((unsigned short)(v.w >> 16)) * q1.w;
  for (int m = 32; m; m >>= 1) d += __shfl_xor(d, m);
  if (lane == 0) s[row] = d;
}

// ---------------- Kernel 4: fused i8 Gram + exp-entropy partials ------------
// R5 skeleton, int8: G*127^2 = Pi * Pi^T via mfma_i32_16x16x64_i8 (exact i32
// accum), BK=128 -> 4 K-steps (half the barriers), 16KB+16KB LDS tiles (same
// 32KB footprint/occupancy as R5), 256KB staged/block (half of R5).
// XOR-swizzle at 16B granules: LDS granule l of row r holds global granule
// l^(r&7) (pre-swizzled global source, linear LDS dest), reads XOR the same.
// Epilogue: partials to collision-free slices Zp/Sp[rb=64][slot=128][128]:
//   row-partials of tile (by,bx), wave wc -> rb=by, slot=2*bx+wc
//   col-partials (mirror, off-diag)      -> rb=bx, slot=2*by+wr
__global__ __launch_bounds__(256) void gram_kernel(
    const unsigned char* __restrict__ Pi, float* __restrict__ Zp,
    float* __restrict__ Sp) {
  __shared__ unsigned char As[128 * 128];  // 16 KB (rows of 128 B)
  __shared__ unsigned char Bs[128 * 128];  // 16 KB

  // XCD-aware bijective remap (2080 = 8 * 260), then triangular decode
  int b = blockIdx.x;
  int i = (b & 7) * 260 + (b >> 3);
  float bi = 64.5f - sqrtf(64.5f * 64.5f - 2.0f * (float)i);
  int by = (int)bi;
  if (by < 0) by = 0;
  while (64 * (by + 1) - ((by + 1) * by) / 2 <= i) ++by;
  while (64 * by - (by * (by - 1)) / 2 > i) --by;
  int bx = by + (i - (64 * by - (by * (by - 1)) / 2));
  bool diag = (bx == by);

  int tid = threadIdx.x, wid = tid >> 6, lane = tid & 63;
  int wr = wid >> 1, wc = wid & 1;
  int l15 = lane & 15, lh = lane >> 4;

  i32x4 acc[4][4];
#pragma unroll
  for (int m = 0; m < 4; ++m)
#pragma unroll
    for (int n = 0; n < 4; ++n)
      acc[m][n] = (i32x4){0, 0, 0, 0};

  int rs = lane >> 3;               // row within 8-row chunk
  int gsw = (lane & 7) ^ rs;        // pre-swizzled 16B granule (XOR involution)
  const unsigned char* abase = Pi + (size_t)(by * 128) * E_DIM;
  const unsigned char* bbase = Pi + (size_t)(bx * 128) * E_DIM;

  for (int kt = 0; kt < 4; ++kt) {
#pragma unroll
    for (int j = 0; j < 4; ++j) {
      int ci = wid * 4 + j;  // 16 chunks of 8 rows
      int r = ci * 8 + rs;
      gload_lds16(abase + (size_t)r * E_DIM + kt * 128 + gsw * 16,
                  (char*)As + ci * 1024);
      gload_lds16(bbase + (size_t)r * E_DIM + kt * 128 + gsw * 16,
                  (char*)Bs + ci * 1024);
    }
    __syncthreads();

    i32x4 af[4][2], bfr[4][2];
#pragma unroll
    for (int m = 0; m < 4; ++m)
#pragma unroll
      for (int kk = 0; kk < 2; ++kk) {
        int row = wr * 64 + m * 16 + l15;
        int g = (kk * 4 + lh) ^ (row & 7);
        af[m][kk] = *(const i32x4*)(As + row * 128 + g * 16);
      }
#pragma unroll
    for (int n = 0; n < 4; ++n)
#pragma unroll
      for (int kk = 0; kk < 2; ++kk) {
        int row = wc * 64 + n * 16 + l15;
        int g = (kk * 4 + lh) ^ (row & 7);
        bfr[n][kk] = *(const i32x4*)(Bs + row * 128 + g * 16);
      }

#pragma unroll
    for (int kk = 0; kk < 2; ++kk)
#pragma unroll
      for (int m = 0; m < 4; ++m)
#pragma unroll
        for (int n = 0; n < 4; ++n)
          acc[m][n] = __builtin_amdgcn_mfma_i32_16x16x64_i8(
              af[m][kk], bfr[n][kk], acc[m][n], 0, 0, 0);
    if (kt < 3) __syncthreads();
  }

  // epilogue: g = acc/127^2; row partials (reduce over l15) + col partials
  const float invq = 1.0f / 16129.0f;
  float zc[4], sc[4];
#pragma unroll
  for (int n = 0; n < 4; ++n) { zc[n] = 0.f; sc[n] = 0.f; }

  int slotR = bx * 2 + wc;
#pragma unroll
  for (int m = 0; m < 4; ++m) {
#pragma unroll
    for (int reg = 0; reg < 4; ++reg) {
      float z = 0.f, s = 0.f;
#pragma unroll
      for (int n = 0; n < 4; ++n) {
        float g = (float)acc[m][n][reg] * invq;
        float e = __expf(g);
        z += e;
        s += e * g;
        zc[n] += e;
        sc[n] += e * g;
      }
      for (int msk = 8; msk; msk >>= 1) {
        z += __shfl_xor(z, msk);
        s += __shfl_xor(s, msk);
      }
      if (l15 == 0) {
        int rowin = wr * 64 + m * 16 + lh * 4 + reg;
        size_t idx = (size_t)by * 16384 + (size_t)slotR * 128 + rowin;
        Zp[idx] = z;
        Sp[idx] = s;
      }
    }
  }
  if (!diag) {
    int slotC = by * 2 + wr;
#pragma unroll
    for (int n = 0; n < 4; ++n) {
      float z = zc[n], s = sc[n];
      z += __shfl_xor(z, 16); s += __shfl_xor(s, 16);
      z += __shfl_xor(z, 32); s += __shfl_xor(s, 32);
      if (lh == 0) {
        int colin = wc * 64 + n * 16 + l15;
        size_t idx = (size_t)bx * 16384 + (size_t)slotC * 128 + colin;
        Zp[idx] = z;
        Sp[idx] = s;
      }
    }
  }
}

// ---------------- Kernel 5: fold 128 slots/row -> per-row entropy -----------
__global__ __launch_bounds__(256) void reduce_kernel(
    const float* __restrict__ Zp, const float* __restrict__ Sp,
    float* __restrict__ Hrow) {
  __shared__ float zbuf[128], sbuf[128];
  int rb = blockIdx.x;
  int t = threadIdx.x;
  int row = t & 127;
  const float* src = (t >= 128) ? Sp : Zp;
  size_t base = (size_t)rb * 16384 + row;
  float acc = 0.f;
#pragma unroll 8
  for (int sl = 0; sl < 128; ++sl) acc += src[base + (size_t)sl * 128];
  if (t >= 128) sbuf[row] = acc; else zbuf[row] = acc;
  __syncthreads();
  if (t < 128) {
    float z = zbuf[t], s2 = sbuf[t];
    Hrow[rb * 128 + t] = logf(z) - s2 / z;
  }
}

// ---------------- Kernel 6: finalize ----------------------------------------
__device__ inline float bsum(float v, volatile float* red) {
  int lane = threadIdx.x & 63, wid = threadIdx.x >> 6;
  for (int k = 32; k; k >>= 1) v += __shfl_xor(v, k);
  __syncthreads();
  if (lane == 0) red[wid] = v;
  __syncthreads();
  float r = 0.f;
  if (wid == 0) {
    r = (lane < 16) ? red[lane] : 0.f;
    for (int k = 8; k; k >>= 1) r += __shfl_xor(r, k);
  }
  if (threadIdx.x == 0) red[16] = r;
  __syncthreads();
  return red[16];
}

__device__ inline float bmax(float v, volatile float* red) {
  int lane = threadIdx.x & 63, wid = threadIdx.x >> 6;
  for (int k = 32; k; k >>= 1) v = fmaxf(v, __shfl_xor(v, k));
  __syncthreads();
  if (lane == 0) red[wid] = v;
  __syncthreads();
  float r = -3.4e38f;
  if (wid == 0) {
    r = (lane < 16) ? red[lane] : -3.4e38f;
    for (int k = 8; k; k >>= 1) r = fmaxf(r, __shfl_xor(r, k));
  }
  if (threadIdx.x == 0) red[16] = r;
  __syncthreads();
  return red[16];
}

__global__ __launch_bounds__(1024) void final_kernel(
    const float* __restrict__ s, const float* __restrict__ Hrow,
    float* __restrict__ out) {
  __shared__ float red[17];
  int tid = threadIdx.x;

  float m = -3.4e38f;
  for (int i = tid; i < C_DIM; i += 1024) m = fmaxf(m, s[i]);
  m = bmax(m, red);

  float z = 0.f, sw = 0.f;
  for (int i = tid; i < C_DIM; i += 1024) {
    float t = s[i] - m;
    float e = __expf(t);
    z += e;
    sw += e * t;
  }
  z = bsum(z, red);
  sw = bsum(sw, red);
  float H2 = logf(z) - sw / z;

  float h = 0.f;
  for (int i = tid; i < C_DIM; i += 1024) h += Hrow[i];
  h = bsum(h, red);

  if (tid == 0) out[0] = h / (float)C_DIM + H2;
}

extern "C" void kernel_launch(void* const* d_in, const int* in_sizes, int n_in,
                              void* d_out, int out_size, void* d_ws, size_t ws_size,
                              hipStream_t stream) {
  const float* P = (const float*)d_in[0];
  float* out = (float*)d_out;

  char* ws = (char*)d_ws;
  unsigned* Pb = (unsigned*)ws;                                    // 8 MB bf16
  unsigned* Pi = (unsigned*)(ws + ((size_t)8 << 20));              // 4 MB i8
  float* Zp = (float*)(ws + ((size_t)12 << 20));                   // 4 MB
  float* Sp = (float*)(ws + ((size_t)16 << 20));                   // 4 MB
  float* q = (float*)(ws + ((size_t)20 << 20));                    // 2 KB
  float* s = (float*)(ws + ((size_t)20 << 20) + 4096);             // 32 KB
  float* Hrow = (float*)(ws + ((size_t)20 << 20) + 4096 + 32768);  // 32 KB

  hipMemsetAsync(q, 0, 2048, stream);  // only q needs zeroing

  norm_kernel<<<C_DIM / 4, 256, 0, stream>>>(P, Pb, Pi);
  qsum_kernel<<<C_DIM / 128, 256, 0, stream>>>((const unsigned short*)Pb, q);
  ssum_kernel<<<C_DIM / 4, 256, 0, stream>>>((const unsigned short*)Pb, q, s);
  gram_kernel<<<2080, 256, 0, stream>>>((const unsigned char*)Pi, Zp, Sp);
  reduce_kernel<<<64, 256, 0, stream>>>(Zp, Sp, Hrow);
  final_kernel<<<1, 1024, 0, stream>>>(s, Hrow, out);
}